// Round 3
// baseline (953.055 us; speedup 1.0000x reference)
//
#include <hip/hip_runtime.h>

#define NB 64
#define NC 64
#define NH 112
#define NW 112
#define NHW (NH*NW)          // 12544
#define NTILES (NHW/64)      // 196
#define S_CHUNKS 8
#define BN_EPS 1e-5f

__device__ __forceinline__ float bf2f(unsigned short u) {
    return __uint_as_float(((unsigned int)u) << 16);
}
__device__ __forceinline__ float bfl(unsigned int u) { return __uint_as_float(u << 16); }
__device__ __forceinline__ float bfh(unsigned int u) { return __uint_as_float(u & 0xffff0000u); }
__device__ __forceinline__ unsigned short f2bf(float f) {
    unsigned int u = __float_as_uint(f);
    return (unsigned short)((u + 0x7fffu + ((u >> 16) & 1u)) >> 16);
}

// dtype-agnostic scalar load: F32 -> float, else bf16 bits
template<bool F32>
__device__ __forceinline__ float ld1(const void* p, size_t i) {
    if constexpr (F32) return ((const float*)p)[i];
    else               return bf2f(((const unsigned short*)p)[i]);
}

// Detect fp32 data read as ushorts: lo-half mantissa words hit exp==0xFF
// (NaN pattern) with p~1/256; bf16 N(0,1) data never has exp==0xFF.
// Scans first 8192 ushorts (= 4096 floats if fp32): E[hits]=16, P(miss)=e^-16.
__device__ __forceinline__ bool detect_f32(const unsigned short* x) {
    int cnt = 0;
    for (int i = threadIdx.x; i < 8192; i += 256) {
        unsigned short u = x[i];
        cnt += ((u & 0x7F80u) == 0x7F80u) ? 1 : 0;
    }
    #pragma unroll
    for (int d = 1; d < 64; d <<= 1) cnt += __shfl_xor(cnt, d, 64);
    __shared__ int dsh[4];
    int wid = threadIdx.x >> 6;
    if ((threadIdx.x & 63) == 0) dsh[wid] = cnt;
    __syncthreads();
    int total = dsh[0] + dsh[1] + dsh[2] + dsh[3];
    __syncthreads();
    return total >= 2;
}

// ---------------------------------------------------------------------------
// Kernel 1: fused value/key 1x1 convs + BN + channel softmax + context matmul.
// Grid: NB*S_CHUNKS=512 blocks, 256 threads. atomicAdd into ctx[b][64][64].
// LDS 48KB: WvT/WmT fp32 + Xt fp32; KT/VT (bf16) alias the dead Xt buffer.
// ---------------------------------------------------------------------------
template<bool F32>
__device__ void ctx_impl(const void* __restrict__ xv, const void* __restrict__ Wv,
                         const void* __restrict__ bv, const void* __restrict__ Wm,
                         const void* __restrict__ bm, const void* __restrict__ g_,
                         const void* __restrict__ be_, const void* __restrict__ me_,
                         const void* __restrict__ va_, float* __restrict__ ctx,
                         float* WvT, float* WmT, float* Xt)
{
    const int tid  = threadIdx.x;
    const int b    = blockIdx.x / S_CHUNKS;
    const int s    = blockIdx.x % S_CHUNKS;
    const int lane = tid & 63;
    const int wid  = tid >> 6;
    unsigned short* KT = (unsigned short*)Xt;        // [pos][o], 8 KB
    unsigned short* VT = ((unsigned short*)Xt) + 4096; // [pos][o], 8 KB

    for (int k = 0; k < 16; ++k) {
        int idx = k * 256 + tid;           // = o*64 + c
        int o = idx >> 6, c = idx & 63;
        WvT[c * 64 + o] = ld1<F32>(Wv, idx);
        WmT[c * 64 + o] = ld1<F32>(Wm, idx);
    }

    const int o = lane;
    const float bv_o = ld1<F32>(bv, o);
    const float bm_o = ld1<F32>(bm, o);
    const float me_o = ld1<F32>(me_, o);
    const float sc_o = ld1<F32>(g_, o) * (1.0f / sqrtf(ld1<F32>(va_, o) + BN_EPS));
    const float be_o = ld1<F32>(be_, o);

    float cacc[4][4];
    #pragma unroll
    for (int ii = 0; ii < 4; ++ii)
        #pragma unroll
        for (int jj = 0; jj < 4; ++jj) cacc[ii][jj] = 0.0f;

    const int i0 = (tid >> 4) << 2;
    const int j0 = (tid & 15) << 2;
    const int pbase = wid << 4;
    const size_t xbase = (size_t)b * (NC * NHW);

    for (int t = s; t < NTILES; t += S_CHUNKS) {
        __syncthreads();  // prev-iter KT/VT readers done; weights visible (1st iter via next sync)

        // stage X tile as fp32 [c][p]
        if constexpr (F32) {
            const float* xp = (const float*)xv + xbase + (size_t)t * 64;
            #pragma unroll
            for (int k = 0; k < 4; ++k) {
                int q = k * 256 + tid;
                int c = q >> 4, p4 = (q & 15) << 2;
                float4 v = *(const float4*)(xp + (size_t)c * NHW + p4);
                *(float4*)(&Xt[(c << 6) + p4]) = v;
            }
        } else {
            const unsigned short* xp = (const unsigned short*)xv + xbase + (size_t)t * 64;
            #pragma unroll
            for (int k = 0; k < 4; ++k) {
                int q = k * 256 + tid;
                int c = q >> 4, p4 = (q & 15) << 2;
                uint2 v = *(const uint2*)(xp + (size_t)c * NHW + p4);
                float4 f; f.x = bfl(v.x); f.y = bfh(v.x); f.z = bfl(v.y); f.w = bfh(v.y);
                *(float4*)(&Xt[(c << 6) + p4]) = f;
            }
        }
        __syncthreads();

        // conv phase: lane = out channel, wave covers 16 positions
        float va[16], ka[16];
        #pragma unroll
        for (int p = 0; p < 16; ++p) { va[p] = bv_o; ka[p] = bm_o; }

        #pragma unroll 2
        for (int c = 0; c < 64; ++c) {
            const float wv = WvT[(c << 6) + o];
            const float wm = WmT[(c << 6) + o];
            const float4* xr = (const float4*)&Xt[(c << 6) + pbase];
            float4 x0 = xr[0], x1 = xr[1], x2 = xr[2], x3 = xr[3];
            float xf[16] = { x0.x, x0.y, x0.z, x0.w, x1.x, x1.y, x1.z, x1.w,
                             x2.x, x2.y, x2.z, x2.w, x3.x, x3.y, x3.z, x3.w };
            #pragma unroll
            for (int p = 0; p < 16; ++p) {
                va[p] = fmaf(wv, xf[p], va[p]);
                ka[p] = fmaf(wm, xf[p], ka[p]);
            }
        }
        __syncthreads();  // Xt fully consumed -> safe to overwrite as KT/VT

        // BN + channel softmax (across lanes) + store K,V tiles (bf16)
        #pragma unroll
        for (int p = 0; p < 16; ++p) {
            float kb = fmaf(ka[p] - me_o, sc_o, be_o);
            float mx = kb;
            #pragma unroll
            for (int d = 1; d < 64; d <<= 1) mx = fmaxf(mx, __shfl_xor(mx, d, 64));
            float e = __expf(kb - mx);
            float ss = e;
            #pragma unroll
            for (int d = 1; d < 64; d <<= 1) ss += __shfl_xor(ss, d, 64);
            float kf = e / ss;
            int pos = pbase + p;
            KT[(pos << 6) + o] = f2bf(kf);
            VT[(pos << 6) + o] = f2bf(va[p]);
        }
        __syncthreads();

        // ctx[i][j] += sum_n K[n][i] * V[n][j]
        #pragma unroll 2
        for (int n = 0; n < 64; ++n) {
            const uint2 ku = *(const uint2*)(&KT[(n << 6) + i0]);
            const uint2 vu = *(const uint2*)(&VT[(n << 6) + j0]);
            float ki[4] = { bfl(ku.x), bfh(ku.x), bfl(ku.y), bfh(ku.y) };
            float vj[4] = { bfl(vu.x), bfh(vu.x), bfl(vu.y), bfh(vu.y) };
            #pragma unroll
            for (int ii = 0; ii < 4; ++ii)
                #pragma unroll
                for (int jj = 0; jj < 4; ++jj)
                    cacc[ii][jj] = fmaf(ki[ii], vj[jj], cacc[ii][jj]);
        }
    }

    float* cb = ctx + ((size_t)b << 12);
    #pragma unroll
    for (int ii = 0; ii < 4; ++ii)
        #pragma unroll
        for (int jj = 0; jj < 4; ++jj)
            atomicAdd(&cb[(i0 + ii) * 64 + (j0 + jj)], cacc[ii][jj]);
}

__global__ __launch_bounds__(256) void ctx_kernel(
    const void* __restrict__ x, const void* __restrict__ Wv, const void* __restrict__ bv,
    const void* __restrict__ Wm, const void* __restrict__ bm, const void* __restrict__ g_,
    const void* __restrict__ be_, const void* __restrict__ me_, const void* __restrict__ va_,
    float* __restrict__ ctx)
{
    __shared__ float WvT[4096];   // 16 KB
    __shared__ float WmT[4096];   // 16 KB
    __shared__ float Xt[4096];    // 16 KB (aliased by KT/VT after conv phase)
    if (detect_f32((const unsigned short*)x))
        ctx_impl<true >(x, Wv, bv, Wm, bm, g_, be_, me_, va_, ctx, WvT, WmT, Xt);
    else
        ctx_impl<false>(x, Wv, bv, Wm, bm, g_, be_, me_, va_, ctx, WvT, WmT, Xt);
}

// ---------------------------------------------------------------------------
// Kernel 2: per-(b,c) plane — recompute 9 dynamic weights from ctx (sigmoid +
// grouped fc) then depthwise 3x3 conv, pad 1. Grid: NB*NC=4096 blocks.
// ---------------------------------------------------------------------------
template<bool F32>
__device__ void dwconv_impl(const void* __restrict__ xv, const float* __restrict__ ctx,
                            const void* __restrict__ Wfc, const void* __restrict__ bfc,
                            void* __restrict__ outv, float* wsm, float* attS)
{
    const int bc = blockIdx.x;
    const int b = bc >> 6, i = bc & 63;
    const int tid = threadIdx.x, lane = tid & 63, wid = tid >> 6;

    if (wid == 0) {
        float cv = ctx[((size_t)b << 12) + (i << 6) + lane];
        attS[lane] = 1.0f / (1.0f + __expf(-cv));
    }
    __syncthreads();

    for (int j = wid; j < 9; j += 4) {
        float p = attS[lane] * ld1<F32>(Wfc, (size_t)(i * 9 + j) * 64 + lane);
        #pragma unroll
        for (int d = 1; d < 64; d <<= 1) p += __shfl_xor(p, d, 64);
        if (lane == 0) wsm[j] = p + ld1<F32>(bfc, i * 9 + j);
    }
    __syncthreads();

    const float w0 = wsm[0], w1 = wsm[1], w2 = wsm[2],
                w3 = wsm[3], w4 = wsm[4], w5 = wsm[5],
                w6 = wsm[6], w7 = wsm[7], w8 = wsm[8];
    const size_t base = (size_t)bc * NHW;

    for (int idx = tid; idx < NHW; idx += 256) {
        int y  = idx / NW;
        int xx = idx - y * NW;
        float sum;
        if (y >= 1 && y <= NH - 2 && xx >= 1 && xx <= NW - 2) {
            sum = w0 * ld1<F32>(xv, base + idx - NW - 1) + w1 * ld1<F32>(xv, base + idx - NW) + w2 * ld1<F32>(xv, base + idx - NW + 1)
                + w3 * ld1<F32>(xv, base + idx - 1)      + w4 * ld1<F32>(xv, base + idx)      + w5 * ld1<F32>(xv, base + idx + 1)
                + w6 * ld1<F32>(xv, base + idx + NW - 1) + w7 * ld1<F32>(xv, base + idx + NW) + w8 * ld1<F32>(xv, base + idx + NW + 1);
        } else {
            sum = 0.0f;
            const float wr[9] = { w0, w1, w2, w3, w4, w5, w6, w7, w8 };
            #pragma unroll
            for (int dy = -1; dy <= 1; ++dy)
                #pragma unroll
                for (int dx = -1; dx <= 1; ++dx) {
                    int yy = y + dy, xc = xx + dx;
                    if (yy >= 0 && yy < NH && xc >= 0 && xc < NW)
                        sum += wr[(dy + 1) * 3 + (dx + 1)] * ld1<F32>(xv, base + yy * NW + xc);
                }
        }
        if constexpr (F32) ((float*)outv)[base + idx] = sum;
        else               ((unsigned short*)outv)[base + idx] = f2bf(sum);
    }
}

__global__ __launch_bounds__(256) void dwconv_kernel(
    const void* __restrict__ x, const float* __restrict__ ctx,
    const void* __restrict__ Wfc, const void* __restrict__ bfc, void* __restrict__ out)
{
    __shared__ float wsm[12];
    __shared__ float attS[64];
    if (detect_f32((const unsigned short*)x))
        dwconv_impl<true >(x, ctx, Wfc, bfc, out, wsm, attS);
    else
        dwconv_impl<false>(x, ctx, Wfc, bfc, out, wsm, attS);
}

extern "C" void kernel_launch(void* const* d_in, const int* in_sizes, int n_in,
                              void* d_out, int out_size, void* d_ws, size_t ws_size,
                              hipStream_t stream) {
    const void* x     = d_in[0];
    const void* Wv    = d_in[1];
    const void* bv    = d_in[2];
    const void* Wm    = d_in[3];
    const void* bm    = d_in[4];
    const void* gamma = d_in[5];
    const void* beta  = d_in[6];
    const void* mean  = d_in[7];
    const void* var   = d_in[8];
    const void* Wfc   = d_in[9];
    const void* bfc   = d_in[10];

    float* ctx = (float*)d_ws;   // exactly 64*64*64*4 = 1,048,576 bytes — total ws use

    hipMemsetAsync(ctx, 0, (size_t)NB * NC * NC * sizeof(float), stream);
    ctx_kernel<<<NB * S_CHUNKS, 256, 0, stream>>>(x, Wv, bv, Wm, bm, gamma, beta, mean, var, ctx);
    dwconv_kernel<<<NB * NC, 256, 0, stream>>>(x, ctx, Wfc, bfc, d_out);
}